// Round 4
// baseline (110.127 us; speedup 1.0000x reference)
//
#include <hip/hip_runtime.h>
#include <hip/hip_bf16.h>

typedef __attribute__((ext_vector_type(4))) float f32x4;
typedef __attribute__((ext_vector_type(8))) short bf16x8;

#define H1S 72  // padded bf16 stride for h1 tile (16B-aligned rows)

struct Smem {
    float inp[384];
    float part[4][64];
    float base[64];
    float sub[8][64];
    __align__(16) short h1hi[128 * H1S];
    __align__(16) short h1lo[128 * H1S];
};

template<bool ISF32>
__device__ __forceinline__ float ldin(const void* p, int i) {
    if constexpr (ISF32) return ((const float*)p)[i];
    else return __bfloat162float(((const __hip_bfloat16*)p)[i]);
}

__device__ __forceinline__ short bf16bits(float v) {
    __hip_bfloat16 h = __float2bfloat16(v);
    return *(const short*)&h;
}

template<bool ISF32>
__device__ void qtran_body(Smem& sm,
    const void* __restrict__ hidden, const void* __restrict__ actions,
    const void* __restrict__ w1, const void* __restrict__ b1,
    const void* __restrict__ w2, const void* __restrict__ b2,
    const void* __restrict__ w3, const void* __restrict__ b3,
    void* __restrict__ out, int b, int t)
{
    const int lane = t & 63;
    const int wv = t >> 6;
    const int q = lane >> 4;
    const int n = lane & 15;

    // ---- stage base input vector (real actions) into LDS as f32 ----
    for (int r = t; r < 384; r += 256) {
        const int j = r / 48;
        const int k = r - j * 48;
        float v;
        if (k < 32) v = ldin<ISF32>(hidden, (b * 8 + j) * 32 + k);
        else        v = ldin<ISF32>(actions, (b * 8 + j) * 16 + (k - 32));
        sm.inp[r] = v;
    }

    // ---- W2 B-fragments, split hi/lo bf16; B[k][n]: n=lane&15, k=quad*8+j ----
    bf16x8 bhi[2][4], blo[2][4];
    #pragma unroll
    for (int ks = 0; ks < 2; ++ks)
      #pragma unroll
      for (int nt = 0; nt < 4; ++nt)
        #pragma unroll
        for (int j = 0; j < 8; ++j) {
            const float wvv = ldin<ISF32>(w2, (ks * 32 + q * 8 + j) * 64 + nt * 16 + n);
            const short hb = bf16bits(wvv);
            __hip_bfloat16 hh = *(const __hip_bfloat16*)&hb;
            bhi[ks][nt][j] = hb;
            blo[ks][nt][j] = bf16bits(wvv - __bfloat162float(hh));
        }

    __syncthreads();

    // ---- base1 = inp @ W1 : wave wv covers K-quarter [wv*96, wv*96+96) ----
    {
        float p = 0.f;
        const int r0 = wv * 96;
        #pragma unroll 8
        for (int r = r0; r < r0 + 96; ++r)
            p = fmaf(sm.inp[r], ldin<ISF32>(w1, r * 64 + lane), p);
        sm.part[wv][lane] = p;
    }
    __syncthreads();
    if (t < 64)
        sm.base[t] = ldin<ISF32>(b1, t)
                   + sm.part[0][t] + sm.part[1][t] + sm.part[2][t] + sm.part[3][t];

    // ---- sub[g][f] = actions[b,g] . W1_g ----
    for (int idx = t; idx < 512; idx += 256) {
        const int g = idx >> 6, f = idx & 63;
        const int rb = g * 48 + 32;
        float s = 0.f;
        #pragma unroll
        for (int c = 0; c < 16; ++c)
            s = fmaf(sm.inp[rb + c], ldin<ISF32>(w1, (rb + c) * 64 + f), s);
        sm.sub[g][f] = s;
    }
    __syncthreads();

    // ---- h1 for all 128 items (item = g*16 + a), split hi/lo bf16 into LDS ----
    #pragma unroll 4
    for (int i = 0; i < 32; ++i) {
        const int idx = i * 256 + t;
        const int item = idx >> 6, f = idx & 63;
        const int g = item >> 4, a = item & 15;
        const float pre = sm.base[f] - sm.sub[g][f]
                        + ldin<ISF32>(w1, (g * 48 + 32 + a) * 64 + f);
        const float h1v = fmaxf(pre, 0.f);
        const short hb = bf16bits(h1v);
        __hip_bfloat16 hh = *(const __hip_bfloat16*)&hb;
        sm.h1hi[item * H1S + f] = hb;
        sm.h1lo[item * H1S + f] = bf16bits(h1v - __bfloat162float(hh));
    }
    __syncthreads();

    // ---- layer 2: 32 items/wave x W2 via split-bf16 mfma_f32_16x16x32_bf16 ----
    f32x4 acc[2][4];
    #pragma unroll
    for (int mt = 0; mt < 2; ++mt)
      #pragma unroll
      for (int nt = 0; nt < 4; ++nt)
        acc[mt][nt] = (f32x4){0.f, 0.f, 0.f, 0.f};

    #pragma unroll
    for (int ks = 0; ks < 2; ++ks) {
        bf16x8 ahi[2], alo[2];
        #pragma unroll
        for (int mt = 0; mt < 2; ++mt) {
            const int item = wv * 32 + mt * 16 + n;   // A[m=lane&15][k=quad*8+j]
            ahi[mt] = *(const bf16x8*)&sm.h1hi[item * H1S + ks * 32 + q * 8];
            alo[mt] = *(const bf16x8*)&sm.h1lo[item * H1S + ks * 32 + q * 8];
        }
        #pragma unroll
        for (int mt = 0; mt < 2; ++mt)
          #pragma unroll
          for (int nt = 0; nt < 4; ++nt) {
            acc[mt][nt] = __builtin_amdgcn_mfma_f32_16x16x32_bf16(
                ahi[mt], bhi[ks][nt], acc[mt][nt], 0, 0, 0);
            acc[mt][nt] = __builtin_amdgcn_mfma_f32_16x16x32_bf16(
                ahi[mt], blo[ks][nt], acc[mt][nt], 0, 0, 0);
            acc[mt][nt] = __builtin_amdgcn_mfma_f32_16x16x32_bf16(
                alo[mt], bhi[ks][nt], acc[mt][nt], 0, 0, 0);
          }
    }

    // ---- epilogue: h2 = relu(acc + b2); qv = h2 . w3 + b3 ----
    float b2f[4], w3f[4];
    #pragma unroll
    for (int nt = 0; nt < 4; ++nt) {
        b2f[nt] = ldin<ISF32>(b2, nt * 16 + n);
        w3f[nt] = ldin<ISF32>(w3, nt * 16 + n);
    }
    const float b3f = ldin<ISF32>(b3, 0);

    #pragma unroll
    for (int mt = 0; mt < 2; ++mt) {
      #pragma unroll
      for (int r = 0; r < 4; ++r) {
        float p = 0.f;
        #pragma unroll
        for (int nt = 0; nt < 4; ++nt) {
            const float h2 = fmaxf(acc[mt][nt][r] + b2f[nt], 0.f);  // D: row=q*4+r, col=n
            p = fmaf(h2, w3f[nt], p);
        }
        p += __shfl_xor(p, 1);
        p += __shfl_xor(p, 2);
        p += __shfl_xor(p, 4);
        p += __shfl_xor(p, 8);
        if (n == mt * 4 + r) {
            const int item = wv * 32 + mt * 16 + q * 4 + r;
            if constexpr (ISF32)
                ((float*)out)[b * 128 + item] = p + b3f;
            else
                ((__hip_bfloat16*)out)[b * 128 + item] = __float2bfloat16(p + b3f);
        }
      }
    }
}

__global__ __launch_bounds__(256) void qtran_cf_kernel(
    const void* __restrict__ hidden, const void* __restrict__ actions,
    const void* __restrict__ w1, const void* __restrict__ b1,
    const void* __restrict__ w2, const void* __restrict__ b2,
    const void* __restrict__ w3, const void* __restrict__ b3,
    void* __restrict__ out)
{
    __shared__ Smem sm;
    // ---- dtype vote: f32 low-half shorts look like random mantissa bits;
    //      packed-bf16 even elements have sane exponents or are +-0 ----
    const unsigned int* hw = (const unsigned int*)hidden;
    int cnt = 0;
    #pragma unroll
    for (int i = 0; i < 32; ++i) {
        const unsigned int w = hw[i];
        const unsigned int lo = w & 0xFFFFu;
        const unsigned int ex = (lo >> 7) & 0xFFu;
        cnt += ((ex >= 100u && ex <= 140u) || (lo & 0x7FFFu) == 0u) ? 1 : 0;
    }
    const bool isf32 = (cnt < 16);

    const int b = blockIdx.x;
    const int t = threadIdx.x;
    if (isf32)
        qtran_body<true>(sm, hidden, actions, w1, b1, w2, b2, w3, b3, out, b, t);
    else
        qtran_body<false>(sm, hidden, actions, w1, b1, w2, b2, w3, b3, out, b, t);
}

extern "C" void kernel_launch(void* const* d_in, const int* in_sizes, int n_in,
                              void* d_out, int out_size, void* d_ws, size_t ws_size,
                              hipStream_t stream) {
    qtran_cf_kernel<<<2048, 256, 0, stream>>>(
        d_in[0], d_in[1], d_in[2], d_in[3], d_in[4], d_in[5], d_in[6], d_in[7],
        d_out);
}

// Round 5
// 90.812 us; speedup vs baseline: 1.2127x; 1.2127x over previous
//
#include <hip/hip_runtime.h>
#include <hip/hip_bf16.h>

typedef __attribute__((ext_vector_type(4))) float f32x4;
typedef __attribute__((ext_vector_type(8))) short bf16x8;
typedef __attribute__((ext_vector_type(4))) short s16x4;

#define H1S 72  // padded bf16 stride (144 B rows: 16B-aligned, banks rotate by 4/item)

struct Smem {
    float inp[384];          // base input vector (real actions), f32
    float base[64];          // base1 = inp @ W1 + b1
    float sub[8][64];        // sub[g][f] = actions[b,g] . W1_g
    union {                  // part's last read (base compute) is barrier-separated
        float part[4][64];   //   from h1's first write -> safe overlay
        struct { __align__(16) short hi[128 * H1S];
                 __align__(16) short lo[128 * H1S]; } h1;
    } u;
};

template<bool ISF32>
__device__ __forceinline__ float ldin(const void* p, int i) {
    if constexpr (ISF32) return ((const float*)p)[i];
    else return __bfloat162float(((const __hip_bfloat16*)p)[i]);
}

template<bool ISF32>
__device__ __forceinline__ f32x4 ldq(const void* p, int i) {
    if constexpr (ISF32) return *(const f32x4*)((const float*)p + i);
    else {
        const __hip_bfloat16* q = (const __hip_bfloat16*)p + i;
        return (f32x4){__bfloat162float(q[0]), __bfloat162float(q[1]),
                       __bfloat162float(q[2]), __bfloat162float(q[3])};
    }
}

__device__ __forceinline__ short bf16bits(float v) {
    __hip_bfloat16 h = __float2bfloat16(v);
    return *(const short*)&h;
}
__device__ __forceinline__ float bf16val(short s) {
    return __bfloat162float(*(const __hip_bfloat16*)&s);
}

__device__ __forceinline__ bool vote_isf32(const void* hidden) {
    const unsigned int* hw = (const unsigned int*)hidden;
    int cnt = 0;
    #pragma unroll
    for (int i = 0; i < 32; ++i) {
        const unsigned int w = hw[i];
        const unsigned int lo = w & 0xFFFFu;
        const unsigned int ex = (lo >> 7) & 0xFFu;
        cnt += ((ex >= 100u && ex <= 140u) || (lo & 0x7FFFu) == 0u) ? 1 : 0;
    }
    return cnt < 16;
}

// ---- prep: swizzle W2 into MFMA B-fragment order, split hi/lo bf16 ----
// layout: wsfrag[((ks*4+nt)*64+lane)*8 + j] (hi), +4096 (lo)
template<bool ISF32>
__device__ void w2prep_body(const void* w2, short* wsfrag, int idx0) {
    #pragma unroll
    for (int i = 0; i < 2; ++i) {
        const int idx = idx0 + i * 2048;            // 0..4095
        const int j = idx & 7;
        const int lane = (idx >> 3) & 63;
        const int nt = (idx >> 9) & 3;
        const int ks = idx >> 11;
        const int src = (ks * 32 + (lane >> 4) * 8 + j) * 64 + nt * 16 + (lane & 15);
        const float v = ldin<ISF32>(w2, src);
        const short hb = bf16bits(v);
        wsfrag[idx] = hb;
        wsfrag[4096 + idx] = bf16bits(v - bf16val(hb));
    }
}

__global__ __launch_bounds__(256) void w2prep_kernel(
    const void* __restrict__ hidden, const void* __restrict__ w2,
    short* __restrict__ wsfrag) {
    const int idx0 = blockIdx.x * 256 + threadIdx.x;
    if (vote_isf32(hidden)) w2prep_body<true>(w2, wsfrag, idx0);
    else                    w2prep_body<false>(w2, wsfrag, idx0);
}

template<bool ISF32>
__device__ void qtran_body(Smem& sm,
    const void* __restrict__ hidden, const void* __restrict__ actions,
    const void* __restrict__ w1, const void* __restrict__ b1,
    const void* __restrict__ w2, const void* __restrict__ b2,
    const void* __restrict__ w3, const void* __restrict__ b3,
    void* __restrict__ out, const short* __restrict__ wsfrag, int b, int t)
{
    const int lane = t & 63;
    const int wv = t >> 6;
    const int q = lane >> 4;
    const int n = lane & 15;
    const int fq = lane & 15;     // f-quad id within wave
    const int rofs = lane >> 4;   // r-offset group

    // ---- phase 0: stage input vector (f32x4 loads) ----
    if (t < 64) {
        const int j = t >> 3, k4 = (t & 7) * 4;
        *(f32x4*)&sm.inp[j * 48 + k4] = ldq<ISF32>(hidden, (b * 8 + j) * 32 + k4);
    } else if (t < 96) {
        const int i = t - 64;                       // 0..31
        const int j = i >> 2, c4 = (i & 3) * 4;
        *(f32x4*)&sm.inp[j * 48 + 32 + c4] = ldq<ISF32>(actions, (b * 8 + j) * 16 + c4);
    }
    __syncthreads();

    // ---- phase 1: base1 partials; wave wv covers r in [wv*96, wv*96+96) ----
    {
        f32x4 a4 = (f32x4){0.f, 0.f, 0.f, 0.f};
        const int r0 = wv * 96 + rofs;
        #pragma unroll 8
        for (int p = 0; p < 24; ++p) {
            const int r = r0 + p * 4;
            const float xv = sm.inp[r];
            const f32x4 wq = ldq<ISF32>(w1, r * 64 + fq * 4);
            #pragma unroll
            for (int c = 0; c < 4; ++c) a4[c] = fmaf(xv, wq[c], a4[c]);
        }
        #pragma unroll
        for (int c = 0; c < 4; ++c) {
            a4[c] += __shfl_xor(a4[c], 16);
            a4[c] += __shfl_xor(a4[c], 32);
        }
        if (rofs == 0) *(f32x4*)&sm.u.part[wv][fq * 4] = a4;
    }

    // ---- phase 2: sub[g][f] = actions[b,g] . W1_g (no barrier: reads only inp) ----
    {
        const int g = t >> 5;                        // 8 agents x 32 threads
        const int s = t & 31;
        const int sfq = s & 15, srof = s >> 4;       // 2 r per pass
        const int rb = g * 48 + 32;
        f32x4 a4 = (f32x4){0.f, 0.f, 0.f, 0.f};
        #pragma unroll
        for (int p = 0; p < 8; ++p) {
            const int c = srof + p * 2;
            const float xv = sm.inp[rb + c];
            const f32x4 wq = ldq<ISF32>(w1, (rb + c) * 64 + sfq * 4);
            #pragma unroll
            for (int cc = 0; cc < 4; ++cc) a4[cc] = fmaf(xv, wq[cc], a4[cc]);
        }
        #pragma unroll
        for (int cc = 0; cc < 4; ++cc) a4[cc] += __shfl_xor(a4[cc], 16);
        if (srof == 0) *(f32x4*)&sm.sub[g][sfq * 4] = a4;
    }
    __syncthreads();

    // ---- phase 3: base = b1 + sum of partials ----
    if (t < 64)
        sm.base[t] = ldin<ISF32>(b1, t) + sm.u.part[0][t] + sm.u.part[1][t]
                   + sm.u.part[2][t] + sm.u.part[3][t];
    __syncthreads();

    // ---- phase 4: h1 for 128 items, split hi/lo bf16 into LDS ----
    {
        const int itm = t >> 4;                      // 16 items per pass
        const int hfq = t & 15;
        const f32x4 bs = *(const f32x4*)&sm.base[hfq * 4];
        #pragma unroll
        for (int p = 0; p < 8; ++p) {
            const int item = p * 16 + itm;
            const int g = item >> 4, a = item & 15;
            const f32x4 wq = ldq<ISF32>(w1, (g * 48 + 32 + a) * 64 + hfq * 4);
            const f32x4 sb = *(const f32x4*)&sm.sub[g][hfq * 4];
            s16x4 hi, lo;
            #pragma unroll
            for (int c = 0; c < 4; ++c) {
                const float v = fmaxf(bs[c] - sb[c] + wq[c], 0.f);
                const short hb = bf16bits(v);
                hi[c] = hb;
                lo[c] = bf16bits(v - bf16val(hb));
            }
            *(s16x4*)&sm.u.h1.hi[item * H1S + hfq * 4] = hi;
            *(s16x4*)&sm.u.h1.lo[item * H1S + hfq * 4] = lo;
        }
    }
    __syncthreads();

    // ---- phase 5: layer 2, 32 items/wave, split-bf16 mfma_f32_16x16x32_bf16 ----
    f32x4 acc[2][4];
    #pragma unroll
    for (int mt = 0; mt < 2; ++mt)
      #pragma unroll
      for (int nt = 0; nt < 4; ++nt)
        acc[mt][nt] = (f32x4){0.f, 0.f, 0.f, 0.f};

    #pragma unroll
    for (int ks = 0; ks < 2; ++ks) {
        bf16x8 ahi[2], alo[2], bhi[4], blo[4];
        #pragma unroll
        for (int mt = 0; mt < 2; ++mt) {
            const int item = wv * 32 + mt * 16 + n;  // A[m=lane&15][k=quad*8+j]
            ahi[mt] = *(const bf16x8*)&sm.u.h1.hi[item * H1S + ks * 32 + q * 8];
            alo[mt] = *(const bf16x8*)&sm.u.h1.lo[item * H1S + ks * 32 + q * 8];
        }
        if (wsfrag) {
            #pragma unroll
            for (int nt = 0; nt < 4; ++nt) {
                const int fb = ((ks * 4 + nt) * 64 + lane) * 8;
                bhi[nt] = *(const bf16x8*)&wsfrag[fb];
                blo[nt] = *(const bf16x8*)&wsfrag[4096 + fb];
            }
        } else {
            #pragma unroll
            for (int nt = 0; nt < 4; ++nt)
                #pragma unroll
                for (int j = 0; j < 8; ++j) {
                    const float v = ldin<ISF32>(w2, (ks * 32 + q * 8 + j) * 64 + nt * 16 + n);
                    const short hb = bf16bits(v);
                    bhi[nt][j] = hb;
                    blo[nt][j] = bf16bits(v - bf16val(hb));
                }
        }
        #pragma unroll
        for (int mt = 0; mt < 2; ++mt)
          #pragma unroll
          for (int nt = 0; nt < 4; ++nt) {
            acc[mt][nt] = __builtin_amdgcn_mfma_f32_16x16x32_bf16(
                ahi[mt], bhi[nt], acc[mt][nt], 0, 0, 0);
            acc[mt][nt] = __builtin_amdgcn_mfma_f32_16x16x32_bf16(
                ahi[mt], blo[nt], acc[mt][nt], 0, 0, 0);
            acc[mt][nt] = __builtin_amdgcn_mfma_f32_16x16x32_bf16(
                alo[mt], bhi[nt], acc[mt][nt], 0, 0, 0);
          }
    }

    // ---- epilogue: h2 = relu(acc + b2); qv = h2 . w3 + b3 ----
    float b2f[4], w3f[4];
    #pragma unroll
    for (int nt = 0; nt < 4; ++nt) {
        b2f[nt] = ldin<ISF32>(b2, nt * 16 + n);
        w3f[nt] = ldin<ISF32>(w3, nt * 16 + n);
    }
    const float b3f = ldin<ISF32>(b3, 0);

    #pragma unroll
    for (int mt = 0; mt < 2; ++mt) {
      #pragma unroll
      for (int r = 0; r < 4; ++r) {
        float p = 0.f;
        #pragma unroll
        for (int nt = 0; nt < 4; ++nt) {
            const float h2 = fmaxf(acc[mt][nt][r] + b2f[nt], 0.f); // D: row=q*4+r, col=n
            p = fmaf(h2, w3f[nt], p);
        }
        p += __shfl_xor(p, 1);
        p += __shfl_xor(p, 2);
        p += __shfl_xor(p, 4);
        p += __shfl_xor(p, 8);
        if (n == mt * 4 + r) {
            const int item = wv * 32 + mt * 16 + q * 4 + r;
            if constexpr (ISF32) ((float*)out)[b * 128 + item] = p + b3f;
            else ((__hip_bfloat16*)out)[b * 128 + item] = __float2bfloat16(p + b3f);
        }
      }
    }
}

__global__ __launch_bounds__(256, 4) void qtran_cf_kernel(
    const void* __restrict__ hidden, const void* __restrict__ actions,
    const void* __restrict__ w1, const void* __restrict__ b1,
    const void* __restrict__ w2, const void* __restrict__ b2,
    const void* __restrict__ w3, const void* __restrict__ b3,
    void* __restrict__ out, const short* __restrict__ wsfrag)
{
    __shared__ Smem sm;
    const bool isf32 = vote_isf32(hidden);
    const int b = blockIdx.x;
    const int t = threadIdx.x;
    if (isf32)
        qtran_body<true>(sm, hidden, actions, w1, b1, w2, b2, w3, b3, out, wsfrag, b, t);
    else
        qtran_body<false>(sm, hidden, actions, w1, b1, w2, b2, w3, b3, out, wsfrag, b, t);
}

extern "C" void kernel_launch(void* const* d_in, const int* in_sizes, int n_in,
                              void* d_out, int out_size, void* d_ws, size_t ws_size,
                              hipStream_t stream) {
    short* wsfrag = (ws_size >= 16384) ? (short*)d_ws : nullptr;
    if (wsfrag)
        w2prep_kernel<<<8, 256, 0, stream>>>(d_in[0], d_in[4], wsfrag);
    qtran_cf_kernel<<<2048, 256, 0, stream>>>(
        d_in[0], d_in[1], d_in[2], d_in[3], d_in[4], d_in[5], d_in[6], d_in[7],
        d_out, wsfrag);
}

// Round 6
// 84.846 us; speedup vs baseline: 1.2980x; 1.0703x over previous
//
#include <hip/hip_runtime.h>
#include <hip/hip_bf16.h>

typedef __attribute__((ext_vector_type(4))) float f32x4;
typedef __attribute__((ext_vector_type(8))) short bf16x8;
typedef __attribute__((ext_vector_type(4))) short s16x4;

#define H1S 72  // padded bf16 stride (144 B rows: 16B-aligned)

struct Smem {
    float inp[384];          // base input vector (real actions), f32
    float base[64];          // b1 + hidden-part of layer 1 (no action rows)
    float sub[8][64];        // sub[g][f] = W1 row of agent g's real action
    int   sel[8];            // real-action index per agent
    union {                  // part's last read is barrier-separated from h1's first write
        float part[4][64];
        __align__(16) short h1[128 * H1S];  // h1 in bf16 (hi only)
    } u;
};

template<bool ISF32>
__device__ __forceinline__ float ldin(const void* p, int i) {
    if constexpr (ISF32) return ((const float*)p)[i];
    else return __bfloat162float(((const __hip_bfloat16*)p)[i]);
}

template<bool ISF32>
__device__ __forceinline__ f32x4 ldq(const void* p, int i) {
    if constexpr (ISF32) return *(const f32x4*)((const float*)p + i);
    else {
        const __hip_bfloat16* q = (const __hip_bfloat16*)p + i;
        return (f32x4){__bfloat162float(q[0]), __bfloat162float(q[1]),
                       __bfloat162float(q[2]), __bfloat162float(q[3])};
    }
}

__device__ __forceinline__ short bf16bits(float v) {
    __hip_bfloat16 h = __float2bfloat16(v);
    return *(const short*)&h;
}
__device__ __forceinline__ float bf16val(short s) {
    return __bfloat162float(*(const __hip_bfloat16*)&s);
}

__device__ __forceinline__ bool word_looks_bf16(unsigned int w) {
    const unsigned int lo = w & 0xFFFFu;
    const unsigned int ex = (lo >> 7) & 0xFFu;
    return (ex >= 100u && ex <= 140u) || (lo & 0x7FFFu) == 0u;
}

// per-thread vote (used only by tiny prep kernel)
__device__ __forceinline__ bool vote_isf32_scalar(const void* hidden) {
    const unsigned int* hw = (const unsigned int*)hidden;
    int cnt = 0;
    #pragma unroll
    for (int i = 0; i < 32; ++i) cnt += word_looks_bf16(hw[i]) ? 1 : 0;
    return cnt < 16;
}

// ---- prep: swizzle W2 into MFMA B-fragment order, split hi/lo bf16 ----
// layout: wsfrag[((ks*4+nt)*64+lane)*8 + j] (hi), +4096 (lo)
template<bool ISF32>
__device__ void w2prep_body(const void* w2, short* wsfrag, int idx0) {
    #pragma unroll
    for (int i = 0; i < 2; ++i) {
        const int idx = idx0 + i * 2048;            // 0..4095
        const int j = idx & 7;
        const int lane = (idx >> 3) & 63;
        const int nt = (idx >> 9) & 3;
        const int ks = idx >> 11;
        const int src = (ks * 32 + (lane >> 4) * 8 + j) * 64 + nt * 16 + (lane & 15);
        const float v = ldin<ISF32>(w2, src);
        const short hb = bf16bits(v);
        wsfrag[idx] = hb;
        wsfrag[4096 + idx] = bf16bits(v - bf16val(hb));
    }
}

__global__ __launch_bounds__(256) void w2prep_kernel(
    const void* __restrict__ hidden, const void* __restrict__ w2,
    short* __restrict__ wsfrag) {
    const int idx0 = blockIdx.x * 256 + threadIdx.x;
    if (vote_isf32_scalar(hidden)) w2prep_body<true>(w2, wsfrag, idx0);
    else                           w2prep_body<false>(w2, wsfrag, idx0);
}

template<bool ISF32>
__device__ void qtran_body(Smem& sm,
    const void* __restrict__ hidden, const void* __restrict__ actions,
    const void* __restrict__ w1, const void* __restrict__ b1,
    const void* __restrict__ w2, const void* __restrict__ b2,
    const void* __restrict__ w3, const void* __restrict__ b3,
    void* __restrict__ out, const short* __restrict__ wsfrag, int b, int t)
{
    const int lane = t & 63;
    const int wv = t >> 6;
    const int q = lane >> 4;
    const int n = lane & 15;
    const int fq = lane & 15;     // f-quad id within wave
    const int rofs = lane >> 4;   // r-offset group

    // ---- phase 0: stage input vector (f32x4 loads) ----
    if (t < 64) {
        const int j = t >> 3, k4 = (t & 7) * 4;
        *(f32x4*)&sm.inp[j * 48 + k4] = ldq<ISF32>(hidden, (b * 8 + j) * 32 + k4);
    } else if (t < 96) {
        const int i = t - 64;                       // 0..31
        const int j = i >> 2, c4 = (i & 3) * 4;
        *(f32x4*)&sm.inp[j * 48 + 32 + c4] = ldq<ISF32>(actions, (b * 8 + j) * 16 + c4);
    }
    __syncthreads();

    // ---- phase 1a: find each agent's real-action index (one-hot) ----
    if (t < 128) {
        const int g = t >> 4, a = t & 15;
        if (sm.inp[g * 48 + 32 + a] > 0.5f) sm.sel[g] = a;
    }

    // ---- phase 1: hidden-row layer-1 partials; wave wv covers 64 of 256 rows ----
    {
        f32x4 a4 = (f32x4){0.f, 0.f, 0.f, 0.f};
        #pragma unroll 8
        for (int p = 0; p < 16; ++p) {
            const int hr = wv * 64 + p * 4 + rofs;  // hidden-row index 0..255
            const int r = (hr >> 5) * 48 + (hr & 31);
            const float xv = sm.inp[r];
            const f32x4 wq = ldq<ISF32>(w1, r * 64 + fq * 4);
            #pragma unroll
            for (int c = 0; c < 4; ++c) a4[c] = fmaf(xv, wq[c], a4[c]);
        }
        #pragma unroll
        for (int c = 0; c < 4; ++c) {
            a4[c] += __shfl_xor(a4[c], 16);
            a4[c] += __shfl_xor(a4[c], 32);
        }
        if (rofs == 0) *(f32x4*)&sm.u.part[wv][fq * 4] = a4;
    }
    __syncthreads();

    // ---- phase 2: sub[g] = W1 row of selected action (direct load) ----
    if (t < 128) {
        const int g = t >> 4, f4 = (t & 15) * 4;
        *(f32x4*)&sm.sub[g][f4] =
            ldq<ISF32>(w1, (g * 48 + 32 + sm.sel[g]) * 64 + f4);
    }
    // ---- phase 3: base = b1 + sum of hidden partials (action part added later) ----
    else if (t >= 128 && t < 192) {
        const int f = t - 128;
        sm.base[f] = ldin<ISF32>(b1, f) + sm.u.part[0][f] + sm.u.part[1][f]
                   + sm.u.part[2][f] + sm.u.part[3][f];
    }
    __syncthreads();

    // ---- phase 4: h1 for 128 items -> bf16 LDS ----
    {
        const int itm = t >> 4;                      // 16 items per pass
        const int hfq = t & 15;
        f32x4 S = *(const f32x4*)&sm.sub[0][hfq * 4];
        #pragma unroll
        for (int g = 1; g < 8; ++g) {
            const f32x4 sg = *(const f32x4*)&sm.sub[g][hfq * 4];
            #pragma unroll
            for (int c = 0; c < 4; ++c) S[c] += sg[c];
        }
        f32x4 bs = *(const f32x4*)&sm.base[hfq * 4];
        #pragma unroll
        for (int c = 0; c < 4; ++c) bs[c] += S[c];   // base incl. all real actions
        #pragma unroll
        for (int p = 0; p < 8; ++p) {
            const int item = p * 16 + itm;
            const int g = item >> 4, a = item & 15;
            const f32x4 wq = ldq<ISF32>(w1, (g * 48 + 32 + a) * 64 + hfq * 4);
            const f32x4 sb = *(const f32x4*)&sm.sub[g][hfq * 4];
            s16x4 hi;
            #pragma unroll
            for (int c = 0; c < 4; ++c)
                hi[c] = bf16bits(fmaxf(bs[c] - sb[c] + wq[c], 0.f));
            *(s16x4*)&sm.u.h1[item * H1S + hfq * 4] = hi;
        }
    }
    __syncthreads();

    // ---- phase 5: layer 2, 32 items/wave; W2 split hi/lo, mfma 16x16x32 bf16 ----
    f32x4 acc[2][4];
    #pragma unroll
    for (int mt = 0; mt < 2; ++mt)
      #pragma unroll
      for (int nt = 0; nt < 4; ++nt)
        acc[mt][nt] = (f32x4){0.f, 0.f, 0.f, 0.f};

    #pragma unroll
    for (int ks = 0; ks < 2; ++ks) {
        bf16x8 ahi[2];
        #pragma unroll
        for (int mt = 0; mt < 2; ++mt) {
            const int item = wv * 32 + mt * 16 + n;  // A[m=lane&15][k=quad*8+j]
            ahi[mt] = *(const bf16x8*)&sm.u.h1[item * H1S + ks * 32 + q * 8];
        }
        #pragma unroll
        for (int nt = 0; nt < 4; ++nt) {
            bf16x8 bhi, blo;
            if (wsfrag) {
                const int fb = ((ks * 4 + nt) * 64 + lane) * 8;
                bhi = *(const bf16x8*)&wsfrag[fb];
                blo = *(const bf16x8*)&wsfrag[4096 + fb];
            } else {
                #pragma unroll
                for (int j = 0; j < 8; ++j) {
                    const float v = ldin<ISF32>(w2, (ks * 32 + q * 8 + j) * 64 + nt * 16 + n);
                    const short hb = bf16bits(v);
                    bhi[j] = hb;
                    blo[j] = bf16bits(v - bf16val(hb));
                }
            }
            #pragma unroll
            for (int mt = 0; mt < 2; ++mt) {
                acc[mt][nt] = __builtin_amdgcn_mfma_f32_16x16x32_bf16(
                    ahi[mt], bhi, acc[mt][nt], 0, 0, 0);
                acc[mt][nt] = __builtin_amdgcn_mfma_f32_16x16x32_bf16(
                    ahi[mt], blo, acc[mt][nt], 0, 0, 0);
            }
        }
    }

    // ---- epilogue: h2 = relu(acc + b2); qv = h2 . w3 + b3 ----
    float b2f[4], w3f[4];
    #pragma unroll
    for (int nt = 0; nt < 4; ++nt) {
        b2f[nt] = ldin<ISF32>(b2, nt * 16 + n);
        w3f[nt] = ldin<ISF32>(w3, nt * 16 + n);
    }
    const float b3f = ldin<ISF32>(b3, 0);

    #pragma unroll
    for (int mt = 0; mt < 2; ++mt) {
      #pragma unroll
      for (int r = 0; r < 4; ++r) {
        float p = 0.f;
        #pragma unroll
        for (int nt = 0; nt < 4; ++nt) {
            const float h2 = fmaxf(acc[mt][nt][r] + b2f[nt], 0.f); // D: row=q*4+r, col=n
            p = fmaf(h2, w3f[nt], p);
        }
        p += __shfl_xor(p, 1);
        p += __shfl_xor(p, 2);
        p += __shfl_xor(p, 4);
        p += __shfl_xor(p, 8);
        if (n == mt * 4 + r) {
            const int item = wv * 32 + mt * 16 + q * 4 + r;
            if constexpr (ISF32) ((float*)out)[b * 128 + item] = p + b3f;
            else ((__hip_bfloat16*)out)[b * 128 + item] = __float2bfloat16(p + b3f);
        }
      }
    }
}

__global__ __launch_bounds__(256, 6) void qtran_cf_kernel(
    const void* __restrict__ hidden, const void* __restrict__ actions,
    const void* __restrict__ w1, const void* __restrict__ b1,
    const void* __restrict__ w2, const void* __restrict__ b2,
    const void* __restrict__ w3, const void* __restrict__ b3,
    void* __restrict__ out, const short* __restrict__ wsfrag)
{
    __shared__ Smem sm;
    // ---- dtype vote, lane-parallel: each lane tests one of 32 words (x2 coverage) ----
    const unsigned int* hw = (const unsigned int*)hidden;
    const bool pass = word_looks_bf16(hw[threadIdx.x & 31]);
    const unsigned long long m = __ballot(pass);
    const bool isf32 = (__popcll(m) < 32);

    const int b = blockIdx.x;
    const int t = threadIdx.x;
    if (isf32)
        qtran_body<true>(sm, hidden, actions, w1, b1, w2, b2, w3, b3, out, wsfrag, b, t);
    else
        qtran_body<false>(sm, hidden, actions, w1, b1, w2, b2, w3, b3, out, wsfrag, b, t);
}

extern "C" void kernel_launch(void* const* d_in, const int* in_sizes, int n_in,
                              void* d_out, int out_size, void* d_ws, size_t ws_size,
                              hipStream_t stream) {
    short* wsfrag = (ws_size >= 16384) ? (short*)d_ws : nullptr;
    if (wsfrag)
        w2prep_kernel<<<8, 256, 0, stream>>>(d_in[0], d_in[4], wsfrag);
    qtran_cf_kernel<<<2048, 256, 0, stream>>>(
        d_in[0], d_in[1], d_in[2], d_in[3], d_in[4], d_in[5], d_in[6], d_in[7],
        d_out, wsfrag);
}